// Round 7
// baseline (180.572 us; speedup 1.0000x reference)
//
#include <hip/hip_runtime.h>

// DTCWT forward, J=3, B=4 C=64 H=W=256, fp32.
// XLA conv = cross-correlation (no flip). Reflection: half-sample symmetric.
// Level 2+: output pair u, even col/row: sum_k In[refl(4u+2k-8)]*h0b[k] (lo)
//           odd: refl(4u+2k-7)*h0a[k]; highpass swaps phases.
// yh outputs are write-once streams -> nontemporal stores.
// ll1 is never materialized: the level-2 kernel recomputes its 32 needed ll1
// rows directly from x (rowfilter-lo + colfilter-lo), since x is L3-resident.

#define INV_SQRT2 0.7071067811865476f

typedef float nvec4 __attribute__((ext_vector_type(4)));
typedef float nvec2 __attribute__((ext_vector_type(2)));

__device__ __forceinline__ int refl(int i, int n) {
    return i < 0 ? (-i - 1) : (i >= n ? (2 * n - 1 - i) : i);
}
__device__ __forceinline__ void st_nt4(float* p, float4 v) {
    nvec4 w = {v.x, v.y, v.z, v.w};
    __builtin_nontemporal_store(w, (nvec4*)p);
}
__device__ __forceinline__ void st_nt2(float* p, float2 v) {
    nvec2 w = {v.x, v.y};
    __builtin_nontemporal_store(w, (nvec2*)p);
}

// ---------------- Level 1 (highpass bands only; ll never written) ----------
__global__ __launch_bounds__(256, 3)
void dtcwt_l1(const float* __restrict__ x,
              const float* __restrict__ h0o,
              const float* __restrict__ h1o,
              float* __restrict__ yh)     // (256,6,128,128,2)
{
    __shared__ float smem[11440];
    float (*xs)[264]  = (float(*)[264])smem;
    float (*slo)[260] = (float(*)[260])smem;
    float (*shi)[260] = (float(*)[260])(smem + 5720);

    const int img = blockIdx.y;
    const int r0  = blockIdx.x * 16;
    const int tid = threadIdx.x;

    float f0[5], f1[7];
#pragma unroll
    for (int k = 0; k < 5; ++k) f0[k] = h0o[k];
#pragma unroll
    for (int k = 0; k < 7; ++k) f1[k] = h1o[k];

    const float* xim = x + (size_t)img * 65536;

    // phase 1: stage 22 rows (row-reflected), float4 main + scalar col halo
#pragma unroll
    for (int it = 0; it < 6; ++it) {
        int idx = tid + it * 256;
        if (idx < 22 * 64) {
            int lr = idx >> 6, q = idx & 63;
            int gr = refl(r0 - 3 + lr, 256);
            float4 v = *(const float4*)(xim + gr * 256 + 4 * q);
            *(float4*)&xs[lr][4 * q + 4] = v;
        }
    }
    if (tid < 132) {   // cols {-3,-2,-1,256,257,258}
        int lr = tid / 6, h = tid % 6;
        int gr = refl(r0 - 3 + lr, 256);
        int c = (h < 3) ? (h - 3) : (253 + h);
        xs[lr][c + 4] = xim[gr * 256 + refl(c, 256)];
    }
    __syncthreads();

    // phase 2: row filter, 4 cols/thread, into registers.
    float rbuf[6][8];
#pragma unroll
    for (int it = 0; it < 6; ++it) {
        int idx = tid + it * 256;
        if (idx < 22 * 64) {
            int lr = idx >> 6, cp = idx & 63;
            float4 w0 = *(const float4*)&xs[lr][4 * cp];
            float4 w1 = *(const float4*)&xs[lr][4 * cp + 4];
            float4 w2 = *(const float4*)&xs[lr][4 * cp + 8];
            float s[12] = {w0.x, w0.y, w0.z, w0.w,
                           w1.x, w1.y, w1.z, w1.w,
                           w2.x, w2.y, w2.z, w2.w};
#pragma unroll
            for (int e = 0; e < 4; ++e) {
                float alo = 0.f, ahi = 0.f;
#pragma unroll
                for (int k = 0; k < 5; ++k) alo = fmaf(f0[k], s[e + 2 + k], alo);
#pragma unroll
                for (int k = 0; k < 7; ++k) ahi = fmaf(f1[k], s[e + 1 + k], ahi);
                rbuf[it][e]     = alo;
                rbuf[it][e + 4] = ahi;
            }
        }
    }
    __syncthreads();

    // phase 3: write back over xs region
#pragma unroll
    for (int it = 0; it < 6; ++it) {
        int idx = tid + it * 256;
        if (idx < 22 * 64) {
            int lr = idx >> 6, cp = idx & 63;
            *(float4*)&slo[lr][4 * cp] =
                make_float4(rbuf[it][0], rbuf[it][1], rbuf[it][2], rbuf[it][3]);
            *(float4*)&shi[lr][4 * cp] =
                make_float4(rbuf[it][4], rbuf[it][5], rbuf[it][6], rbuf[it][7]);
        }
    }
    __syncthreads();

    // phase 4: fused col filter + q2c, 2x4 output quad per thread (LH/HL/HH only)
    float* yim  = yh + (size_t)img * (6 * 128 * 128 * 2);
#pragma unroll
    for (int it = 0; it < 2; ++it) {
        int idx = tid + it * 256;          // < 512
        int ii = idx >> 6, j = idx & 63;   // out rows 2ii,2ii+1; cols 4j..4j+3
        float sL[8][4], sH[8][4];
#pragma unroll
        for (int t = 0; t < 8; ++t) {
            float4 a = *(const float4*)&slo[2 * ii + t][4 * j];
            float4 b = *(const float4*)&shi[2 * ii + t][4 * j];
            sL[t][0] = a.x; sL[t][1] = a.y; sL[t][2] = a.z; sL[t][3] = a.w;
            sH[t][0] = b.x; sH[t][1] = b.y; sH[t][2] = b.z; sH[t][3] = b.w;
        }
        float aLH[2][4] = {}, aHL[2][4] = {}, aHH[2][4] = {};
#pragma unroll
        for (int k = 0; k < 5; ++k) {
            float fk = f0[k];
#pragma unroll
            for (int e = 0; e < 4; ++e) {
                aHL[0][e] = fmaf(fk, sH[k + 1][e], aHL[0][e]);
                aHL[1][e] = fmaf(fk, sH[k + 2][e], aHL[1][e]);
            }
        }
#pragma unroll
        for (int k = 0; k < 7; ++k) {
            float fk = f1[k];
#pragma unroll
            for (int e = 0; e < 4; ++e) {
                aLH[0][e] = fmaf(fk, sL[k][e],     aLH[0][e]);
                aLH[1][e] = fmaf(fk, sL[k + 1][e], aLH[1][e]);
                aHH[0][e] = fmaf(fk, sH[k][e],     aHH[0][e]);
                aHH[1][e] = fmaf(fk, sH[k + 1][e], aHH[1][e]);
            }
        }
        const int i = (r0 >> 1) + ii;
        const float sc = INV_SQRT2;
        // band -> (plane1, plane2): LH->(0,5), HH->(1,4), HL->(2,3)
#pragma unroll
        for (int band = 0; band < 3; ++band) {
            const float (*S)[4] = (band == 0) ? aLH : (band == 1) ? aHH : aHL;
            int o1 = (band == 0) ? 0 : (band == 1) ? 1 : 2;
            int o2 = (band == 0) ? 5 : (band == 1) ? 4 : 3;
            float r1[4], r2[4];
#pragma unroll
            for (int jj = 0; jj < 2; ++jj) {
                float a = S[0][2 * jj] * sc, b = S[0][2 * jj + 1] * sc;
                float c = S[1][2 * jj] * sc, d = S[1][2 * jj + 1] * sc;
                r1[2 * jj] = a - d; r1[2 * jj + 1] = b + c;
                r2[2 * jj] = a + d; r2[2 * jj + 1] = b - c;
            }
            st_nt4(yim + (size_t)(o1 * 128 + i) * 256 + 4 * j,
                   make_float4(r1[0], r1[1], r1[2], r1[3]));
            st_nt4(yim + (size_t)(o2 * 128 + i) * 256 + 4 * j,
                   make_float4(r2[0], r2[1], r2[2], r2[3]));
        }
    }
}

// ---------------- Level 2 fused: recompute ll1 rows from x ----------------
__global__ __launch_bounds__(256, 4)
void dtcwt_l2_fused(const float* __restrict__ x,
                    const float* __restrict__ h0o,
                    const float* __restrict__ h0a, const float* __restrict__ h0b,
                    const float* __restrict__ h1a, const float* __restrict__ h1b,
                    float* __restrict__ llout,   // ll2 (256,128,128) ws
                    float* __restrict__ yh)      // (256,6,64,64,2)
{
    constexpr int NI = 4, CH2 = 128, CQ = 64, Nj = 64;
    constexpr int NR = 32, NRX = 36, XSTR = 264, YSTR = 260;
    constexpr int LDE = 142, XSZ = NR * LDE, LDY4 = 4 * Nj + 4;

    __shared__ float smem[NRX * XSTR];   // 9504 floats; phases alias (reg-buffered)

    const int img = blockIdx.y;
    const int i0  = blockIdx.x * NI;
    const int tid = threadIdx.x;
    const int rbase = 4 * i0 - 10;

    float f0[5];
#pragma unroll
    for (int k = 0; k < 5; ++k) f0[k] = h0o[k];

    const float* xim = x + (size_t)img * 65536;

    // phase 1: stage 36 x rows (logical l = rbase+t, row-reflected), cols [-2,257]
    float (*xst)[XSTR] = (float(*)[XSTR])smem;   // col c at [c+4]
#pragma unroll
    for (int it = 0; it < 9; ++it) {
        int idx = tid + it * 256;
        int t = idx >> 6, q = idx & 63;
        int gr = refl(rbase + t, 256);
        float4 v = *(const float4*)(xim + gr * 256 + 4 * q);
        *(float4*)&xst[t][4 * q + 4] = v;
    }
    if (tid < 144) {
        int t = tid >> 2, h = tid & 3;
        int gr = refl(rbase + t, 256);
        int c = (h < 2) ? (h - 2) : (254 + h);   // {-2,-1,256,257}
        xst[t][c + 4] = xim[gr * 256 + refl(c, 256)];
    }
    __syncthreads();

    // phase 2: rowfilter-lo on all 36 rows -> regs
    float rbA[9][4];
#pragma unroll
    for (int it = 0; it < 9; ++it) {
        int idx = tid + it * 256;
        int t = idx >> 6, q = idx & 63;
        const float* p = &xst[t][4 * q + 2];     // p[u] = X[refl(4q+u-2)]
        float s[8];
#pragma unroll
        for (int u = 0; u < 4; ++u) {
            float2 v = *(const float2*)(p + 2 * u);
            s[2 * u] = v.x; s[2 * u + 1] = v.y;
        }
#pragma unroll
        for (int e = 0; e < 4; ++e) {
            float a = 0.f;
#pragma unroll
            for (int k = 0; k < 5; ++k) a = fmaf(f0[k], s[e + k], a);
            rbA[it][e] = a;
        }
    }
    __syncthreads();

    // phase 2b: write ylo over staging region
    float (*ylo)[YSTR] = (float(*)[YSTR])smem;   // [36][256]
#pragma unroll
    for (int it = 0; it < 9; ++it) {
        int idx = tid + it * 256;
        int t = idx >> 6, q = idx & 63;
        *(float4*)&ylo[t][4 * q] =
            make_float4(rbA[it][0], rbA[it][1], rbA[it][2], rbA[it][3]);
    }
    __syncthreads();

    // phase 3: colfilter-lo -> 32 ll1 rows in regs. Row lr: logical m=4*i0-8+lr,
    // g'=refl(m); source x-row refl(g'-2+k) is ALWAYS in the direct staged range,
    // at slot refl(g'-2+k)-rbase.
    float rbB[8][4];
#pragma unroll
    for (int it = 0; it < 8; ++it) {
        int idx = tid + it * 256;
        int lr = idx >> 6, q = idx & 63;
        int gp = refl(4 * i0 - 8 + lr, 256);
        float a0 = 0.f, a1 = 0.f, a2 = 0.f, a3 = 0.f;
#pragma unroll
        for (int k = 0; k < 5; ++k) {
            int tk = refl(gp - 2 + k, 256) - rbase;
            float4 v = *(const float4*)&ylo[tk][4 * q];
            a0 = fmaf(f0[k], v.x, a0); a1 = fmaf(f0[k], v.y, a1);
            a2 = fmaf(f0[k], v.z, a2); a3 = fmaf(f0[k], v.w, a3);
        }
        rbB[it][0] = a0; rbB[it][1] = a1; rbB[it][2] = a2; rbB[it][3] = a3;
    }
    // col-halo de-interleave entries m in {-4..-1, 128..131}: one per thread
    int hlr = tid >> 3, hh = tid & 7;
    int hm  = (hh < 4) ? (hh - 4) : (124 + hh);
    int hgp = refl(4 * i0 - 8 + hlr, 256);
    int ccE = refl(2 * hm, 256), ccO = refl(2 * hm + 1, 256);
    float hvE = 0.f, hvO = 0.f;
#pragma unroll
    for (int k = 0; k < 5; ++k) {
        int tk = refl(hgp - 2 + k, 256) - rbase;
        hvE = fmaf(f0[k], ylo[tk][ccE], hvE);
        hvO = fmaf(f0[k], ylo[tk][ccO], hvO);
    }
    __syncthreads();

    // phase 3b: write de-interleaved ll1 rows: xsE[lr][m+4]=ll1[refl(2m)]
    float (*xsE)[LDE] = (float(*)[LDE])smem;
    float (*xsO)[LDE] = (float(*)[LDE])(smem + XSZ);
#pragma unroll
    for (int it = 0; it < 8; ++it) {
        int idx = tid + it * 256;
        int lr = idx >> 6, q = idx & 63;
        *(float2*)&xsE[lr][2 * q + 4] = make_float2(rbB[it][0], rbB[it][2]);
        *(float2*)&xsO[lr][2 * q + 4] = make_float2(rbB[it][1], rbB[it][3]);
    }
    xsE[hlr][hm + 4] = hvE;
    xsO[hlr][hm + 4] = hvO;
    __syncthreads();

    // load downsample filters only now (limit live VGPRs in phases 1-3)
    float fa0[10], fb0[10], fa1[10], fb1[10];
#pragma unroll
    for (int k = 0; k < 10; ++k) {
        fa0[k] = h0a[k]; fb0[k] = h0b[k];
        fa1[k] = h1a[k]; fb1[k] = h1b[k];
    }

    // phase 4: rowdfilt into regs, 2 column-pairs per item (TI2 = 4)
    float rb2[4][8];
#pragma unroll
    for (int it = 0; it < 4; ++it) {
        int idx = tid + it * 256;
        int r = idx % NR, t = idx / NR;
        float e[12], o[12];
#pragma unroll
        for (int u = 0; u < 6; ++u) {
            float2 ve = *(const float2*)&xsE[r][4 * t + 2 * u];
            float2 vo = *(const float2*)&xsO[r][4 * t + 2 * u];
            e[2 * u] = ve.x; e[2 * u + 1] = ve.y;
            o[2 * u] = vo.x; o[2 * u + 1] = vo.y;
        }
        float lE0 = 0.f, lO0 = 0.f, hE0 = 0.f, hO0 = 0.f;
        float lE1 = 0.f, lO1 = 0.f, hE1 = 0.f, hO1 = 0.f;
#pragma unroll
        for (int k = 0; k < 10; ++k) {
            float e0 = e[k], o0 = o[k], e1 = e[k + 2], o1v = o[k + 2];
            lE0 = fmaf(e0, fb0[k], lE0);  lO0 = fmaf(o0, fa0[k], lO0);
            hE0 = fmaf(o0, fa1[k], hE0);  hO0 = fmaf(e0, fb1[k], hO0);
            lE1 = fmaf(e1, fb0[k], lE1);  lO1 = fmaf(o1v, fa0[k], lO1);
            hE1 = fmaf(o1v, fa1[k], hE1); hO1 = fmaf(e1, fb1[k], hO1);
        }
        rb2[it][0] = lE0; rb2[it][1] = lO0; rb2[it][2] = hE0; rb2[it][3] = hO0;
        rb2[it][4] = lE1; rb2[it][5] = lO1; rb2[it][6] = hE1; rb2[it][7] = hO1;
    }
    __syncthreads();

    float (*y4)[LDY4] = (float(*)[LDY4])smem;    // [32][4j+{loE,loO,hiE,hiO}]
#pragma unroll
    for (int it = 0; it < 4; ++it) {
        int idx = tid + it * 256;
        int r = idx % NR, t = idx / NR;
        *(float4*)&y4[r][8 * t]     = make_float4(rb2[it][0], rb2[it][1], rb2[it][2], rb2[it][3]);
        *(float4*)&y4[r][8 * t + 4] = make_float4(rb2[it][4], rb2[it][5], rb2[it][6], rb2[it][7]);
    }
    __syncthreads();

    // phase 5: coldfilt + in-register q2c; thread per (ii, j) 2x2 quad
    float* llo = llout + (size_t)img * CH2 * CH2;
    float* yim = yh + (size_t)img * (6 * CQ * CQ * 2);
    {
        int ii = tid / CQ, j = tid % CQ;          // NI*CQ == 256 exactly
        float ll00=0,ll01=0,ll10=0,ll11=0, lh00=0,lh01=0,lh10=0,lh11=0;
        float hl00=0,hl01=0,hl10=0,hl11=0, hh00=0,hh01=0,hh10=0,hh11=0;
#pragma unroll
        for (int k = 0; k < 10; ++k) {
            int ra = 4 * ii + 2 * k, rbr = ra + 1;
            float4 A = *(const float4*)&y4[ra][4 * j];    // loE,loO,hiE,hiO
            float4 B = *(const float4*)&y4[rbr][4 * j];
            float a0 = fa0[k], b0 = fb0[k], a1 = fa1[k], b1 = fb1[k];
            ll00 = fmaf(A.x, b0, ll00); ll01 = fmaf(A.y, b0, ll01);
            ll10 = fmaf(B.x, a0, ll10); ll11 = fmaf(B.y, a0, ll11);
            lh00 = fmaf(B.x, a1, lh00); lh01 = fmaf(B.y, a1, lh01);
            lh10 = fmaf(A.x, b1, lh10); lh11 = fmaf(A.y, b1, lh11);
            hl00 = fmaf(A.z, b0, hl00); hl01 = fmaf(A.w, b0, hl01);
            hl10 = fmaf(B.z, a0, hl10); hl11 = fmaf(B.w, a0, hl11);
            hh00 = fmaf(B.z, a1, hh00); hh01 = fmaf(B.w, a1, hh01);
            hh10 = fmaf(A.z, b1, hh10); hh11 = fmaf(A.w, b1, hh11);
        }
        int orow = 2 * (i0 + ii);
        *(float2*)(llo + (size_t)orow * CH2 + 2 * j)       = make_float2(ll00, ll01);
        *(float2*)(llo + (size_t)(orow + 1) * CH2 + 2 * j) = make_float2(ll10, ll11);
        const int i = i0 + ii;
        const float sc = INV_SQRT2;
        float a, b, c, d;
        a = lh00 * sc; b = lh01 * sc; c = lh10 * sc; d = lh11 * sc;
        st_nt2(yim + ((size_t)(0 * CQ + i) * CQ + j) * 2, make_float2(a - d, b + c));
        st_nt2(yim + ((size_t)(5 * CQ + i) * CQ + j) * 2, make_float2(a + d, b - c));
        a = hh00 * sc; b = hh01 * sc; c = hh10 * sc; d = hh11 * sc;
        st_nt2(yim + ((size_t)(1 * CQ + i) * CQ + j) * 2, make_float2(a - d, b + c));
        st_nt2(yim + ((size_t)(4 * CQ + i) * CQ + j) * 2, make_float2(a + d, b - c));
        a = hl00 * sc; b = hl01 * sc; c = hl10 * sc; d = hl11 * sc;
        st_nt2(yim + ((size_t)(2 * CQ + i) * CQ + j) * 2, make_float2(a - d, b + c));
        st_nt2(yim + ((size_t)(3 * CQ + i) * CQ + j) * 2, make_float2(a + d, b - c));
    }
}

// ---------------- Level 3 (reads ll2) ----------------
template <int CI, int NI, bool NT_LL>
__global__ __launch_bounds__(256, 4)
void dtcwt_l2(const float* __restrict__ llin,
              const float* __restrict__ h0a, const float* __restrict__ h0b,
              const float* __restrict__ h1a, const float* __restrict__ h1b,
              float* __restrict__ llout,   // (256, CI/2, CI/2)
              float* __restrict__ yh)      // (256, 6, CI/4, CI/4, 2)
{
    constexpr int CH2  = CI / 2;
    constexpr int CQ   = CI / 4;
    constexpr int Nj   = CI / 4;
    constexpr int NR   = 4 * NI + 16;
    constexpr int LDE  = CI / 2 + 14;
    constexpr int LDY4 = 4 * Nj + 4;
    constexpr int XSZ  = NR * LDE;
    constexpr int SM   = (2 * XSZ > NR * LDY4) ? 2 * XSZ : NR * LDY4;
    constexpr int TIS  = NR * (CI / 4) / 256;
    constexpr int TI2  = NR * (Nj / 2) / 256;

    __shared__ float smem[SM];
    float (*xsE)[LDE] = (float(*)[LDE])smem;
    float (*xsO)[LDE] = (float(*)[LDE])(smem + XSZ);
    float (*y4)[LDY4] = (float(*)[LDY4])smem;

    const int img = blockIdx.y;
    const int i0  = blockIdx.x * NI;
    const int tid = threadIdx.x;

    float fa0[10], fb0[10], fa1[10], fb1[10];
#pragma unroll
    for (int k = 0; k < 10; ++k) {
        fa0[k] = h0a[k]; fb0[k] = h0b[k];
        fa1[k] = h1a[k]; fb1[k] = h1b[k];
    }

    const float* xim = llin + (size_t)img * CI * CI;

#pragma unroll
    for (int it = 0; it < TIS; ++it) {
        int idx = tid + it * 256;
        int lr = idx / (CI / 4), q = idx % (CI / 4);
        int gr = refl(4 * i0 - 8 + lr, CI);
        float4 v = *(const float4*)(xim + (size_t)gr * CI + 4 * q);
        *(float2*)&xsE[lr][2 * q + 4] = make_float2(v.x, v.z);
        *(float2*)&xsO[lr][2 * q + 4] = make_float2(v.y, v.w);
    }
    for (int idx = tid; idx < NR * 8; idx += 256) {
        int lr = idx >> 3, h = idx & 7;
        int gr = refl(4 * i0 - 8 + lr, CI);
        int m = (h < 4) ? (h - 4) : (CI / 2 + h - 4);
        xsE[lr][m + 4] = xim[(size_t)gr * CI + refl(2 * m, CI)];
        xsO[lr][m + 4] = xim[(size_t)gr * CI + refl(2 * m + 1, CI)];
    }
    __syncthreads();

    float rb2[TI2][8];
#pragma unroll
    for (int it = 0; it < TI2; ++it) {
        int idx = tid + it * 256;
        int r = idx % NR, t = idx / NR;
        float e[12], o[12];
#pragma unroll
        for (int u = 0; u < 6; ++u) {
            float2 ve = *(const float2*)&xsE[r][4 * t + 2 * u];
            float2 vo = *(const float2*)&xsO[r][4 * t + 2 * u];
            e[2 * u] = ve.x; e[2 * u + 1] = ve.y;
            o[2 * u] = vo.x; o[2 * u + 1] = vo.y;
        }
        float lE0 = 0.f, lO0 = 0.f, hE0 = 0.f, hO0 = 0.f;
        float lE1 = 0.f, lO1 = 0.f, hE1 = 0.f, hO1 = 0.f;
#pragma unroll
        for (int k = 0; k < 10; ++k) {
            float e0 = e[k], o0 = o[k], e1 = e[k + 2], o1v = o[k + 2];
            lE0 = fmaf(e0, fb0[k], lE0);  lO0 = fmaf(o0, fa0[k], lO0);
            hE0 = fmaf(o0, fa1[k], hE0);  hO0 = fmaf(e0, fb1[k], hO0);
            lE1 = fmaf(e1, fb0[k], lE1);  lO1 = fmaf(o1v, fa0[k], lO1);
            hE1 = fmaf(o1v, fa1[k], hE1); hO1 = fmaf(e1, fb1[k], hO1);
        }
        rb2[it][0] = lE0; rb2[it][1] = lO0; rb2[it][2] = hE0; rb2[it][3] = hO0;
        rb2[it][4] = lE1; rb2[it][5] = lO1; rb2[it][6] = hE1; rb2[it][7] = hO1;
    }
    __syncthreads();

#pragma unroll
    for (int it = 0; it < TI2; ++it) {
        int idx = tid + it * 256;
        int r = idx % NR, t = idx / NR;
        *(float4*)&y4[r][8 * t]     = make_float4(rb2[it][0], rb2[it][1], rb2[it][2], rb2[it][3]);
        *(float4*)&y4[r][8 * t + 4] = make_float4(rb2[it][4], rb2[it][5], rb2[it][6], rb2[it][7]);
    }
    __syncthreads();

    float* llo = llout + (size_t)img * CH2 * CH2;
    float* yim = yh + (size_t)img * (6 * CQ * CQ * 2);
    {
        int ii = tid / CQ, j = tid % CQ;
        float ll00=0,ll01=0,ll10=0,ll11=0, lh00=0,lh01=0,lh10=0,lh11=0;
        float hl00=0,hl01=0,hl10=0,hl11=0, hh00=0,hh01=0,hh10=0,hh11=0;
#pragma unroll
        for (int k = 0; k < 10; ++k) {
            int ra = 4 * ii + 2 * k, rbr = ra + 1;
            float4 A = *(const float4*)&y4[ra][4 * j];
            float4 B = *(const float4*)&y4[rbr][4 * j];
            float a0 = fa0[k], b0 = fb0[k], a1 = fa1[k], b1 = fb1[k];
            ll00 = fmaf(A.x, b0, ll00); ll01 = fmaf(A.y, b0, ll01);
            ll10 = fmaf(B.x, a0, ll10); ll11 = fmaf(B.y, a0, ll11);
            lh00 = fmaf(B.x, a1, lh00); lh01 = fmaf(B.y, a1, lh01);
            lh10 = fmaf(A.x, b1, lh10); lh11 = fmaf(A.y, b1, lh11);
            hl00 = fmaf(A.z, b0, hl00); hl01 = fmaf(A.w, b0, hl01);
            hl10 = fmaf(B.z, a0, hl10); hl11 = fmaf(B.w, a0, hl11);
            hh00 = fmaf(B.z, a1, hh00); hh01 = fmaf(B.w, a1, hh01);
            hh10 = fmaf(A.z, b1, hh10); hh11 = fmaf(A.w, b1, hh11);
        }
        int orow = 2 * (i0 + ii);
        if (NT_LL) {
            st_nt2(llo + (size_t)orow * CH2 + 2 * j,       make_float2(ll00, ll01));
            st_nt2(llo + (size_t)(orow + 1) * CH2 + 2 * j, make_float2(ll10, ll11));
        } else {
            *(float2*)(llo + (size_t)orow * CH2 + 2 * j)       = make_float2(ll00, ll01);
            *(float2*)(llo + (size_t)(orow + 1) * CH2 + 2 * j) = make_float2(ll10, ll11);
        }
        const int i = i0 + ii;
        const float sc = INV_SQRT2;
        float a, b, c, d;
        a = lh00 * sc; b = lh01 * sc; c = lh10 * sc; d = lh11 * sc;
        st_nt2(yim + ((size_t)(0 * CQ + i) * CQ + j) * 2, make_float2(a - d, b + c));
        st_nt2(yim + ((size_t)(5 * CQ + i) * CQ + j) * 2, make_float2(a + d, b - c));
        a = hh00 * sc; b = hh01 * sc; c = hh10 * sc; d = hh11 * sc;
        st_nt2(yim + ((size_t)(1 * CQ + i) * CQ + j) * 2, make_float2(a - d, b + c));
        st_nt2(yim + ((size_t)(4 * CQ + i) * CQ + j) * 2, make_float2(a + d, b - c));
        a = hl00 * sc; b = hl01 * sc; c = hl10 * sc; d = hl11 * sc;
        st_nt2(yim + ((size_t)(2 * CQ + i) * CQ + j) * 2, make_float2(a - d, b + c));
        st_nt2(yim + ((size_t)(3 * CQ + i) * CQ + j) * 2, make_float2(a + d, b - c));
    }
}

extern "C" void kernel_launch(void* const* d_in, const int* in_sizes, int n_in,
                              void* d_out, int out_size, void* d_ws, size_t ws_size,
                              hipStream_t stream)
{
    const float* x   = (const float*)d_in[0];
    const float* h0o = (const float*)d_in[1];
    const float* h1o = (const float*)d_in[2];
    const float* h0a = (const float*)d_in[3];
    const float* h0b = (const float*)d_in[4];
    const float* h1a = (const float*)d_in[5];
    const float* h1b = (const float*)d_in[6];
    float* out = (float*)d_out;

    float* ll2 = (float*)d_ws;            // 4,194,304 floats (16 MB)

    float* ll3 = out;                     //  1,048,576
    float* yh1 = out + 1048576;           // 50,331,648
    float* yh2 = out + 51380224;          // 12,582,912
    float* yh3 = out + 63963136;          //  3,145,728

    dtcwt_l1<<<dim3(16, 256), 256, 0, stream>>>(x, h0o, h1o, yh1);
    dtcwt_l2_fused<<<dim3(16, 256), 256, 0, stream>>>(x, h0o, h0a, h0b, h1a, h1b, ll2, yh2);
    dtcwt_l2<128, 8, true><<<dim3(4, 256), 256, 0, stream>>>(ll2, h0a, h0b, h1a, h1b, ll3, yh3);
}

// Round 8
// 123.196 us; speedup vs baseline: 1.4657x; 1.4657x over previous
//
#include <hip/hip_runtime.h>

// DTCWT forward, J=3, B=4 C=64 H=W=256, fp32.
// XLA conv = cross-correlation (no flip). Reflection: half-sample symmetric.
// Level 2+: output pair u, even col/row: sum_k In[refl(4u+2k-8)]*h0b[k] (lo)
//           odd: refl(4u+2k-7)*h0a[k]; highpass swaps phases.
// yh outputs are write-once streams -> nontemporal stores; ll1/ll2 cached
// (re-read by the next level). l1 row-filter reads x directly from global
// (L1-served overlapping float4s); edge reflection = vector reversal.

#define INV_SQRT2 0.7071067811865476f

typedef float nvec4 __attribute__((ext_vector_type(4)));
typedef float nvec2 __attribute__((ext_vector_type(2)));

__device__ __forceinline__ int refl(int i, int n) {
    return i < 0 ? (-i - 1) : (i >= n ? (2 * n - 1 - i) : i);
}
__device__ __forceinline__ void st_nt4(float* p, float4 v) {
    nvec4 w = {v.x, v.y, v.z, v.w};
    __builtin_nontemporal_store(w, (nvec4*)p);
}
__device__ __forceinline__ void st_nt2(float* p, float2 v) {
    nvec2 w = {v.x, v.y};
    __builtin_nontemporal_store(w, (nvec2*)p);
}

// ---------------- Level 1 ----------------
// slo[22][260] @0, shi[22][260] @5720  (11440 floats = 45.8 KB, 3 blocks/CU)
__global__ __launch_bounds__(256, 3)
void dtcwt_l1(const float* __restrict__ x,
              const float* __restrict__ h0o,
              const float* __restrict__ h1o,
              float* __restrict__ ll,     // (256,256,256) ws
              float* __restrict__ yh)     // (256,6,128,128,2)
{
    __shared__ float smem[11440];
    float (*slo)[260] = (float(*)[260])smem;
    float (*shi)[260] = (float(*)[260])(smem + 5720);

    const int img = blockIdx.y;
    const int r0  = blockIdx.x * 16;
    const int tid = threadIdx.x;

    float f0[5], f1[7];
#pragma unroll
    for (int k = 0; k < 5; ++k) f0[k] = h0o[k];
#pragma unroll
    for (int k = 0; k < 7; ++k) f1[k] = h1o[k];

    const float* xim = x + (size_t)img * 65536;

    // phase A: row filter, 4 cols/thread, direct global reads.
    // s[u] = X[gr][refl(4cp-4+u)], u in [0,12); out col e: lo taps s[e+2+k],
    // hi taps s[e+1+k]. Edge windows are register reversals (half-sample symm).
#pragma unroll
    for (int it = 0; it < 6; ++it) {
        int idx = tid + it * 256;
        if (idx < 22 * 64) {
            int lr = idx >> 6, cp = idx & 63;
            int gr = refl(r0 - 3 + lr, 256);
            const float* row = xim + gr * 256;
            float s[12];
            if (cp == 0) {
                float4 v0 = *(const float4*)(row);
                float4 v1 = *(const float4*)(row + 4);
                s[0] = v0.w; s[1] = v0.z; s[2]  = v0.y; s[3]  = v0.x;
                s[4] = v0.x; s[5] = v0.y; s[6]  = v0.z; s[7]  = v0.w;
                s[8] = v1.x; s[9] = v1.y; s[10] = v1.z; s[11] = v1.w;
            } else if (cp == 63) {
                float4 v0 = *(const float4*)(row + 248);
                float4 v1 = *(const float4*)(row + 252);
                s[0] = v0.x; s[1] = v0.y; s[2]  = v0.z; s[3]  = v0.w;
                s[4] = v1.x; s[5] = v1.y; s[6]  = v1.z; s[7]  = v1.w;
                s[8] = v1.w; s[9] = v1.z; s[10] = v1.y; s[11] = v1.x;
            } else {
                float4 v0 = *(const float4*)(row + 4 * cp - 4);
                float4 v1 = *(const float4*)(row + 4 * cp);
                float4 v2 = *(const float4*)(row + 4 * cp + 4);
                s[0] = v0.x; s[1] = v0.y; s[2]  = v0.z; s[3]  = v0.w;
                s[4] = v1.x; s[5] = v1.y; s[6]  = v1.z; s[7]  = v1.w;
                s[8] = v2.x; s[9] = v2.y; s[10] = v2.z; s[11] = v2.w;
            }
            float alo[4], ahi[4];
#pragma unroll
            for (int e = 0; e < 4; ++e) { alo[e] = 0.f; ahi[e] = 0.f; }
#pragma unroll
            for (int k = 0; k < 5; ++k) {
#pragma unroll
                for (int e = 0; e < 4; ++e) alo[e] = fmaf(f0[k], s[e + 2 + k], alo[e]);
            }
#pragma unroll
            for (int k = 0; k < 7; ++k) {
#pragma unroll
                for (int e = 0; e < 4; ++e) ahi[e] = fmaf(f1[k], s[e + 1 + k], ahi[e]);
            }
            *(float4*)&slo[lr][4 * cp] = make_float4(alo[0], alo[1], alo[2], alo[3]);
            *(float4*)&shi[lr][4 * cp] = make_float4(ahi[0], ahi[1], ahi[2], ahi[3]);
        }
    }
    __syncthreads();

    // phase B: fused col filter + q2c, 2x4 output quad per thread
    float* llim = ll + (size_t)img * 65536;
    float* yim  = yh + (size_t)img * (6 * 128 * 128 * 2);
#pragma unroll
    for (int it = 0; it < 2; ++it) {
        int idx = tid + it * 256;          // < 512
        int ii = idx >> 6, j = idx & 63;   // out rows 2ii,2ii+1; cols 4j..4j+3
        float sL[8][4], sH[8][4];
#pragma unroll
        for (int t = 0; t < 8; ++t) {
            float4 a = *(const float4*)&slo[2 * ii + t][4 * j];
            float4 b = *(const float4*)&shi[2 * ii + t][4 * j];
            sL[t][0] = a.x; sL[t][1] = a.y; sL[t][2] = a.z; sL[t][3] = a.w;
            sH[t][0] = b.x; sH[t][1] = b.y; sH[t][2] = b.z; sH[t][3] = b.w;
        }
        float aLL[2][4] = {}, aLH[2][4] = {}, aHL[2][4] = {}, aHH[2][4] = {};
#pragma unroll
        for (int k = 0; k < 5; ++k) {
            float fk = f0[k];
#pragma unroll
            for (int e = 0; e < 4; ++e) {
                aLL[0][e] = fmaf(fk, sL[k + 1][e], aLL[0][e]);
                aLL[1][e] = fmaf(fk, sL[k + 2][e], aLL[1][e]);
                aHL[0][e] = fmaf(fk, sH[k + 1][e], aHL[0][e]);
                aHL[1][e] = fmaf(fk, sH[k + 2][e], aHL[1][e]);
            }
        }
#pragma unroll
        for (int k = 0; k < 7; ++k) {
            float fk = f1[k];
#pragma unroll
            for (int e = 0; e < 4; ++e) {
                aLH[0][e] = fmaf(fk, sL[k][e],     aLH[0][e]);
                aLH[1][e] = fmaf(fk, sL[k + 1][e], aLH[1][e]);
                aHH[0][e] = fmaf(fk, sH[k][e],     aHH[0][e]);
                aHH[1][e] = fmaf(fk, sH[k + 1][e], aHH[1][e]);
            }
        }
        int orow = r0 + 2 * ii;
        *(float4*)(llim + (size_t)orow * 256 + 4 * j) =
            make_float4(aLL[0][0], aLL[0][1], aLL[0][2], aLL[0][3]);
        *(float4*)(llim + (size_t)(orow + 1) * 256 + 4 * j) =
            make_float4(aLL[1][0], aLL[1][1], aLL[1][2], aLL[1][3]);
        const int i = (r0 >> 1) + ii;
        const float sc = INV_SQRT2;
        // band -> (plane1, plane2): LH->(0,5), HH->(1,4), HL->(2,3)
#pragma unroll
        for (int band = 0; band < 3; ++band) {
            const float (*S)[4] = (band == 0) ? aLH : (band == 1) ? aHH : aHL;
            int o1 = (band == 0) ? 0 : (band == 1) ? 1 : 2;
            int o2 = (band == 0) ? 5 : (band == 1) ? 4 : 3;
            float r1[4], r2[4];
#pragma unroll
            for (int jj = 0; jj < 2; ++jj) {
                float a = S[0][2 * jj] * sc, b = S[0][2 * jj + 1] * sc;
                float c = S[1][2 * jj] * sc, d = S[1][2 * jj + 1] * sc;
                r1[2 * jj] = a - d; r1[2 * jj + 1] = b + c;
                r2[2 * jj] = a + d; r2[2 * jj + 1] = b - c;
            }
            st_nt4(yim + (size_t)(o1 * 128 + i) * 256 + 4 * j,
                   make_float4(r1[0], r1[1], r1[2], r1[3]));
            st_nt4(yim + (size_t)(o2 * 128 + i) * 256 + 4 * j,
                   make_float4(r2[0], r2[1], r2[2], r2[3]));
        }
    }
}

// ---------------- Levels 2+ ----------------
template <int CI, int NI, bool NT_LL>
__global__ __launch_bounds__(256, 4)
void dtcwt_l2(const float* __restrict__ llin,
              const float* __restrict__ h0a, const float* __restrict__ h0b,
              const float* __restrict__ h1a, const float* __restrict__ h1b,
              float* __restrict__ llout,   // (256, CI/2, CI/2)
              float* __restrict__ yh)      // (256, 6, CI/4, CI/4, 2)
{
    constexpr int CH2  = CI / 2;
    constexpr int CQ   = CI / 4;
    constexpr int Nj   = CI / 4;
    constexpr int NR   = 4 * NI + 16;
    constexpr int LDE  = CI / 2 + 14;         // even; %32 == 14 -> 2-way (free)
    constexpr int LDY4 = 4 * Nj + 4;          // float4-interleaved y rows
    constexpr int XSZ  = NR * LDE;
    constexpr int SM   = (2 * XSZ > NR * LDY4) ? 2 * XSZ : NR * LDY4;
    constexpr int TIS  = NR * (CI / 4) / 256; // stage iters (exact)
    constexpr int TI2  = NR * (Nj / 2) / 256; // rowdfilt iters (exact)

    __shared__ float smem[SM];
    float (*xsE)[LDE] = (float(*)[LDE])smem;
    float (*xsO)[LDE] = (float(*)[LDE])(smem + XSZ);
    float (*y4)[LDY4] = (float(*)[LDY4])smem;   // [r][4j+{loE,loO,hiE,hiO}]

    const int img = blockIdx.y;
    const int i0  = blockIdx.x * NI;
    const int tid = threadIdx.x;

    float fa0[10], fb0[10], fa1[10], fb1[10];
#pragma unroll
    for (int k = 0; k < 10; ++k) {
        fa0[k] = h0a[k]; fb0[k] = h0b[k];
        fa1[k] = h1a[k]; fb1[k] = h1b[k];
    }

    const float* xim = llin + (size_t)img * CI * CI;

    // phase 1: stage de-interleaved even/odd cols; xsE[r][m+4]=X[refl(2m)]
#pragma unroll
    for (int it = 0; it < TIS; ++it) {
        int idx = tid + it * 256;
        int lr = idx / (CI / 4), q = idx % (CI / 4);
        int gr = refl(4 * i0 - 8 + lr, CI);
        float4 v = *(const float4*)(xim + (size_t)gr * CI + 4 * q);
        *(float2*)&xsE[lr][2 * q + 4] = make_float2(v.x, v.z);
        *(float2*)&xsO[lr][2 * q + 4] = make_float2(v.y, v.w);
    }
    for (int idx = tid; idx < NR * 8; idx += 256) {  // m in {-4..-1, CI/2..CI/2+3}
        int lr = idx >> 3, h = idx & 7;
        int gr = refl(4 * i0 - 8 + lr, CI);
        int m = (h < 4) ? (h - 4) : (CI / 2 + h - 4);
        xsE[lr][m + 4] = xim[(size_t)gr * CI + refl(2 * m, CI)];
        xsO[lr][m + 4] = xim[(size_t)gr * CI + refl(2 * m + 1, CI)];
    }
    __syncthreads();

    // phase 2: rowdfilt into registers, 2 column-pairs (j0=2t, j0+1) per item.
    // e[u] = xsE[r][4t+u] = X[refl(8t+2u-8)], o[u] = X[refl(8t+2u-7)]
    float rb2[TI2][8];
#pragma unroll
    for (int it = 0; it < TI2; ++it) {
        int idx = tid + it * 256;
        int r = idx % NR, t = idx / NR;
        float e[12], o[12];
#pragma unroll
        for (int u = 0; u < 6; ++u) {
            float2 ve = *(const float2*)&xsE[r][4 * t + 2 * u];
            float2 vo = *(const float2*)&xsO[r][4 * t + 2 * u];
            e[2 * u] = ve.x; e[2 * u + 1] = ve.y;
            o[2 * u] = vo.x; o[2 * u + 1] = vo.y;
        }
        float lE0 = 0.f, lO0 = 0.f, hE0 = 0.f, hO0 = 0.f;
        float lE1 = 0.f, lO1 = 0.f, hE1 = 0.f, hO1 = 0.f;
#pragma unroll
        for (int k = 0; k < 10; ++k) {
            float e0 = e[k], o0 = o[k], e1 = e[k + 2], o1v = o[k + 2];
            lE0 = fmaf(e0, fb0[k], lE0);  lO0 = fmaf(o0, fa0[k], lO0);
            hE0 = fmaf(o0, fa1[k], hE0);  hO0 = fmaf(e0, fb1[k], hO0);
            lE1 = fmaf(e1, fb0[k], lE1);  lO1 = fmaf(o1v, fa0[k], lO1);
            hE1 = fmaf(o1v, fa1[k], hE1); hO1 = fmaf(e1, fb1[k], hO1);
        }
        rb2[it][0] = lE0; rb2[it][1] = lO0; rb2[it][2] = hE0; rb2[it][3] = hO0;
        rb2[it][4] = lE1; rb2[it][5] = lO1; rb2[it][6] = hE1; rb2[it][7] = hO1;
    }
    __syncthreads();

    // phase 3: write y4 over the xs region
#pragma unroll
    for (int it = 0; it < TI2; ++it) {
        int idx = tid + it * 256;
        int r = idx % NR, t = idx / NR;
        *(float4*)&y4[r][8 * t]     = make_float4(rb2[it][0], rb2[it][1], rb2[it][2], rb2[it][3]);
        *(float4*)&y4[r][8 * t + 4] = make_float4(rb2[it][4], rb2[it][5], rb2[it][6], rb2[it][7]);
    }
    __syncthreads();

    // phase 4: coldfilt + in-register q2c; thread per (ii, j) 2x2 quad
    float* llo = llout + (size_t)img * CH2 * CH2;
    float* yim = yh + (size_t)img * (6 * CQ * CQ * 2);
    {
        int ii = tid / CQ, j = tid % CQ;          // NI*CQ == 256 exactly
        float ll00=0,ll01=0,ll10=0,ll11=0, lh00=0,lh01=0,lh10=0,lh11=0;
        float hl00=0,hl01=0,hl10=0,hl11=0, hh00=0,hh01=0,hh10=0,hh11=0;
#pragma unroll
        for (int k = 0; k < 10; ++k) {
            int ra = 4 * ii + 2 * k, rbr = ra + 1;
            float4 A = *(const float4*)&y4[ra][4 * j];    // loE,loO,hiE,hiO
            float4 B = *(const float4*)&y4[rbr][4 * j];
            float a0 = fa0[k], b0 = fb0[k], a1 = fa1[k], b1 = fb1[k];
            ll00 = fmaf(A.x, b0, ll00); ll01 = fmaf(A.y, b0, ll01);
            ll10 = fmaf(B.x, a0, ll10); ll11 = fmaf(B.y, a0, ll11);
            lh00 = fmaf(B.x, a1, lh00); lh01 = fmaf(B.y, a1, lh01);
            lh10 = fmaf(A.x, b1, lh10); lh11 = fmaf(A.y, b1, lh11);
            hl00 = fmaf(A.z, b0, hl00); hl01 = fmaf(A.w, b0, hl01);
            hl10 = fmaf(B.z, a0, hl10); hl11 = fmaf(B.w, a0, hl11);
            hh00 = fmaf(B.z, a1, hh00); hh01 = fmaf(B.w, a1, hh01);
            hh10 = fmaf(A.z, b1, hh10); hh11 = fmaf(A.w, b1, hh11);
        }
        int orow = 2 * (i0 + ii);
        if (NT_LL) {
            st_nt2(llo + (size_t)orow * CH2 + 2 * j,       make_float2(ll00, ll01));
            st_nt2(llo + (size_t)(orow + 1) * CH2 + 2 * j, make_float2(ll10, ll11));
        } else {
            *(float2*)(llo + (size_t)orow * CH2 + 2 * j)       = make_float2(ll00, ll01);
            *(float2*)(llo + (size_t)(orow + 1) * CH2 + 2 * j) = make_float2(ll10, ll11);
        }
        const int i = i0 + ii;
        const float sc = INV_SQRT2;
        float a, b, c, d;
        a = lh00 * sc; b = lh01 * sc; c = lh10 * sc; d = lh11 * sc;
        st_nt2(yim + ((size_t)(0 * CQ + i) * CQ + j) * 2, make_float2(a - d, b + c));
        st_nt2(yim + ((size_t)(5 * CQ + i) * CQ + j) * 2, make_float2(a + d, b - c));
        a = hh00 * sc; b = hh01 * sc; c = hh10 * sc; d = hh11 * sc;
        st_nt2(yim + ((size_t)(1 * CQ + i) * CQ + j) * 2, make_float2(a - d, b + c));
        st_nt2(yim + ((size_t)(4 * CQ + i) * CQ + j) * 2, make_float2(a + d, b - c));
        a = hl00 * sc; b = hl01 * sc; c = hl10 * sc; d = hl11 * sc;
        st_nt2(yim + ((size_t)(2 * CQ + i) * CQ + j) * 2, make_float2(a - d, b + c));
        st_nt2(yim + ((size_t)(3 * CQ + i) * CQ + j) * 2, make_float2(a + d, b - c));
    }
}

extern "C" void kernel_launch(void* const* d_in, const int* in_sizes, int n_in,
                              void* d_out, int out_size, void* d_ws, size_t ws_size,
                              hipStream_t stream)
{
    const float* x   = (const float*)d_in[0];
    const float* h0o = (const float*)d_in[1];
    const float* h1o = (const float*)d_in[2];
    const float* h0a = (const float*)d_in[3];
    const float* h0b = (const float*)d_in[4];
    const float* h1a = (const float*)d_in[5];
    const float* h1b = (const float*)d_in[6];
    float* out = (float*)d_out;

    float* ll1 = (float*)d_ws;            // 16,777,216 floats (64 MB)
    float* ll2 = ll1 + 16777216;          //  4,194,304 floats (16 MB)

    float* ll3 = out;                     //  1,048,576
    float* yh1 = out + 1048576;           // 50,331,648
    float* yh2 = out + 51380224;          // 12,582,912
    float* yh3 = out + 63963136;          //  3,145,728

    dtcwt_l1<<<dim3(16, 256), 256, 0, stream>>>(x, h0o, h1o, ll1, yh1);
    dtcwt_l2<256, 4, false><<<dim3(16, 256), 256, 0, stream>>>(ll1, h0a, h0b, h1a, h1b, ll2, yh2);
    dtcwt_l2<128, 8, true><<<dim3(4, 256), 256, 0, stream>>>(ll2, h0a, h0b, h1a, h1b, ll3, yh3);
}

// Round 9
// 109.525 us; speedup vs baseline: 1.6487x; 1.1248x over previous
//
#include <hip/hip_runtime.h>

// DTCWT forward, J=3, B=4 C=64 H=W=256, fp32.
// XLA conv = cross-correlation (no flip). Reflection: half-sample symmetric.
// Level 2+: output pair u, even col/row: sum_k In[refl(4u+2k-8)]*h0b[k] (lo)
//           odd: refl(4u+2k-7)*h0a[k]; highpass swaps phases.
// yh outputs are write-once streams -> nontemporal stores; ll1/ll2 cached
// (re-read by the next level). LDS is a union: staging dies after the
// row-filter pass (outputs buffered in regs, static indexing).

#define INV_SQRT2 0.7071067811865476f

typedef float nvec4 __attribute__((ext_vector_type(4)));
typedef float nvec2 __attribute__((ext_vector_type(2)));

__device__ __forceinline__ int refl(int i, int n) {
    return i < 0 ? (-i - 1) : (i >= n ? (2 * n - 1 - i) : i);
}
__device__ __forceinline__ void st_nt4(float* p, float4 v) {
    nvec4 w = {v.x, v.y, v.z, v.w};
    __builtin_nontemporal_store(w, (nvec4*)p);
}
__device__ __forceinline__ void st_nt2(float* p, float2 v) {
    nvec2 w = {v.x, v.y};
    __builtin_nontemporal_store(w, (nvec2*)p);
}

// ---------------- Level 1 (round-6 structure) ----------------
// phase 1/2: xs[22][264], col c at [c+4]  (5808 floats)
// phase 3/4: slo[22][260] @0, shi[22][260] @5720  (11440 floats = 45.8 KB)
__global__ __launch_bounds__(256, 3)
void dtcwt_l1(const float* __restrict__ x,
              const float* __restrict__ h0o,
              const float* __restrict__ h1o,
              float* __restrict__ ll,     // (256,256,256) ws
              float* __restrict__ yh)     // (256,6,128,128,2)
{
    __shared__ float smem[11440];
    float (*xs)[264]  = (float(*)[264])smem;
    float (*slo)[260] = (float(*)[260])smem;
    float (*shi)[260] = (float(*)[260])(smem + 5720);

    const int img = blockIdx.y;
    const int r0  = blockIdx.x * 16;
    const int tid = threadIdx.x;

    float f0[5], f1[7];
#pragma unroll
    for (int k = 0; k < 5; ++k) f0[k] = h0o[k];
#pragma unroll
    for (int k = 0; k < 7; ++k) f1[k] = h1o[k];

    const float* xim = x + (size_t)img * 65536;

    // phase 1: stage 22 rows (row-reflected), float4 main + scalar col halo
#pragma unroll
    for (int it = 0; it < 6; ++it) {
        int idx = tid + it * 256;
        if (idx < 22 * 64) {
            int lr = idx >> 6, q = idx & 63;
            int gr = refl(r0 - 3 + lr, 256);
            float4 v = *(const float4*)(xim + gr * 256 + 4 * q);
            *(float4*)&xs[lr][4 * q + 4] = v;
        }
    }
    if (tid < 132) {   // cols {-3,-2,-1,256,257,258}
        int lr = tid / 6, h = tid % 6;
        int gr = refl(r0 - 3 + lr, 256);
        int c = (h < 3) ? (h - 3) : (253 + h);
        xs[lr][c + 4] = xim[gr * 256 + refl(c, 256)];
    }
    __syncthreads();

    // phase 2: row filter, 4 cols/thread, into registers.
    // s[u] = xs[lr][4cp+u] = X[refl(4cp+u-4)]; col e: lo taps s[e+2+k], hi s[e+1+k]
    float rbuf[6][8];
#pragma unroll
    for (int it = 0; it < 6; ++it) {
        int idx = tid + it * 256;
        if (idx < 22 * 64) {
            int lr = idx >> 6, cp = idx & 63;
            float4 w0 = *(const float4*)&xs[lr][4 * cp];
            float4 w1 = *(const float4*)&xs[lr][4 * cp + 4];
            float4 w2 = *(const float4*)&xs[lr][4 * cp + 8];
            float s[12] = {w0.x, w0.y, w0.z, w0.w,
                           w1.x, w1.y, w1.z, w1.w,
                           w2.x, w2.y, w2.z, w2.w};
#pragma unroll
            for (int e = 0; e < 4; ++e) {
                float alo = 0.f, ahi = 0.f;
#pragma unroll
                for (int k = 0; k < 5; ++k) alo = fmaf(f0[k], s[e + 2 + k], alo);
#pragma unroll
                for (int k = 0; k < 7; ++k) ahi = fmaf(f1[k], s[e + 1 + k], ahi);
                rbuf[it][e]     = alo;
                rbuf[it][e + 4] = ahi;
            }
        }
    }
    __syncthreads();

    // phase 3: write back over xs region
#pragma unroll
    for (int it = 0; it < 6; ++it) {
        int idx = tid + it * 256;
        if (idx < 22 * 64) {
            int lr = idx >> 6, cp = idx & 63;
            *(float4*)&slo[lr][4 * cp] =
                make_float4(rbuf[it][0], rbuf[it][1], rbuf[it][2], rbuf[it][3]);
            *(float4*)&shi[lr][4 * cp] =
                make_float4(rbuf[it][4], rbuf[it][5], rbuf[it][6], rbuf[it][7]);
        }
    }
    __syncthreads();

    // phase 4: fused col filter + q2c, 2x4 output quad per thread
    float* llim = ll + (size_t)img * 65536;
    float* yim  = yh + (size_t)img * (6 * 128 * 128 * 2);
#pragma unroll
    for (int it = 0; it < 2; ++it) {
        int idx = tid + it * 256;          // < 512
        int ii = idx >> 6, j = idx & 63;   // out rows 2ii,2ii+1; cols 4j..4j+3
        float sL[8][4], sH[8][4];
#pragma unroll
        for (int t = 0; t < 8; ++t) {
            float4 a = *(const float4*)&slo[2 * ii + t][4 * j];
            float4 b = *(const float4*)&shi[2 * ii + t][4 * j];
            sL[t][0] = a.x; sL[t][1] = a.y; sL[t][2] = a.z; sL[t][3] = a.w;
            sH[t][0] = b.x; sH[t][1] = b.y; sH[t][2] = b.z; sH[t][3] = b.w;
        }
        float aLL[2][4] = {}, aLH[2][4] = {}, aHL[2][4] = {}, aHH[2][4] = {};
#pragma unroll
        for (int k = 0; k < 5; ++k) {
            float fk = f0[k];
#pragma unroll
            for (int e = 0; e < 4; ++e) {
                aLL[0][e] = fmaf(fk, sL[k + 1][e], aLL[0][e]);
                aLL[1][e] = fmaf(fk, sL[k + 2][e], aLL[1][e]);
                aHL[0][e] = fmaf(fk, sH[k + 1][e], aHL[0][e]);
                aHL[1][e] = fmaf(fk, sH[k + 2][e], aHL[1][e]);
            }
        }
#pragma unroll
        for (int k = 0; k < 7; ++k) {
            float fk = f1[k];
#pragma unroll
            for (int e = 0; e < 4; ++e) {
                aLH[0][e] = fmaf(fk, sL[k][e],     aLH[0][e]);
                aLH[1][e] = fmaf(fk, sL[k + 1][e], aLH[1][e]);
                aHH[0][e] = fmaf(fk, sH[k][e],     aHH[0][e]);
                aHH[1][e] = fmaf(fk, sH[k + 1][e], aHH[1][e]);
            }
        }
        int orow = r0 + 2 * ii;
        *(float4*)(llim + (size_t)orow * 256 + 4 * j) =
            make_float4(aLL[0][0], aLL[0][1], aLL[0][2], aLL[0][3]);
        *(float4*)(llim + (size_t)(orow + 1) * 256 + 4 * j) =
            make_float4(aLL[1][0], aLL[1][1], aLL[1][2], aLL[1][3]);
        const int i = (r0 >> 1) + ii;
        const float sc = INV_SQRT2;
        // band -> (plane1, plane2): LH->(0,5), HH->(1,4), HL->(2,3)
#pragma unroll
        for (int band = 0; band < 3; ++band) {
            const float (*S)[4] = (band == 0) ? aLH : (band == 1) ? aHH : aHL;
            int o1 = (band == 0) ? 0 : (band == 1) ? 1 : 2;
            int o2 = (band == 0) ? 5 : (band == 1) ? 4 : 3;
            float r1[4], r2[4];
#pragma unroll
            for (int jj = 0; jj < 2; ++jj) {
                float a = S[0][2 * jj] * sc, b = S[0][2 * jj + 1] * sc;
                float c = S[1][2 * jj] * sc, d = S[1][2 * jj + 1] * sc;
                r1[2 * jj] = a - d; r1[2 * jj + 1] = b + c;
                r2[2 * jj] = a + d; r2[2 * jj + 1] = b - c;
            }
            st_nt4(yim + (size_t)(o1 * 128 + i) * 256 + 4 * j,
                   make_float4(r1[0], r1[1], r1[2], r1[3]));
            st_nt4(yim + (size_t)(o2 * 128 + i) * 256 + 4 * j,
                   make_float4(r2[0], r2[1], r2[2], r2[3]));
        }
    }
}

// ---------------- Levels 2+ ----------------
template <int CI, int NI, bool NT_LL, int MW>
__global__ __launch_bounds__(256, MW)
void dtcwt_l2(const float* __restrict__ llin,
              const float* __restrict__ h0a, const float* __restrict__ h0b,
              const float* __restrict__ h1a, const float* __restrict__ h1b,
              float* __restrict__ llout,   // (256, CI/2, CI/2)
              float* __restrict__ yh)      // (256, 6, CI/4, CI/4, 2)
{
    constexpr int CH2  = CI / 2;
    constexpr int CQ   = CI / 4;
    constexpr int Nj   = CI / 4;
    constexpr int NR   = 4 * NI + 16;
    constexpr int LDE  = CI / 2 + 14;         // %32 == 14 -> 2-way (free)
    constexpr int LDY4 = 4 * Nj + 4;
    constexpr int XSZ  = NR * LDE;
    constexpr int SM   = (2 * XSZ > NR * LDY4) ? 2 * XSZ : NR * LDY4;
    constexpr int TIS  = NR * (CI / 4) / 256; // stage iters (exact)
    constexpr int TI2  = NR * (Nj / 2) / 256; // rowdfilt iters (exact)
    constexpr int TI4  = NI * CQ / 256;       // coldfilt iters (exact)

    __shared__ float smem[SM];
    float (*xsE)[LDE] = (float(*)[LDE])smem;
    float (*xsO)[LDE] = (float(*)[LDE])(smem + XSZ);
    float (*y4)[LDY4] = (float(*)[LDY4])smem;   // [r][4j+{loE,loO,hiE,hiO}]

    const int img = blockIdx.y;
    const int i0  = blockIdx.x * NI;
    const int tid = threadIdx.x;

    float fa0[10], fb0[10], fa1[10], fb1[10];
#pragma unroll
    for (int k = 0; k < 10; ++k) {
        fa0[k] = h0a[k]; fb0[k] = h0b[k];
        fa1[k] = h1a[k]; fb1[k] = h1b[k];
    }

    const float* xim = llin + (size_t)img * CI * CI;

    // phase 1: stage de-interleaved even/odd cols; xsE[r][m+4]=X[refl(2m)]
#pragma unroll
    for (int it = 0; it < TIS; ++it) {
        int idx = tid + it * 256;
        int lr = idx / (CI / 4), q = idx % (CI / 4);
        int gr = refl(4 * i0 - 8 + lr, CI);
        float4 v = *(const float4*)(xim + (size_t)gr * CI + 4 * q);
        *(float2*)&xsE[lr][2 * q + 4] = make_float2(v.x, v.z);
        *(float2*)&xsO[lr][2 * q + 4] = make_float2(v.y, v.w);
    }
    for (int idx = tid; idx < NR * 8; idx += 256) {  // m in {-4..-1, CI/2..CI/2+3}
        int lr = idx >> 3, h = idx & 7;
        int gr = refl(4 * i0 - 8 + lr, CI);
        int m = (h < 4) ? (h - 4) : (CI / 2 + h - 4);
        xsE[lr][m + 4] = xim[(size_t)gr * CI + refl(2 * m, CI)];
        xsO[lr][m + 4] = xim[(size_t)gr * CI + refl(2 * m + 1, CI)];
    }
    __syncthreads();

    // phase 2: rowdfilt into registers, 2 column-pairs (j0=2t, j0+1) per item.
    // e[u] = xsE[r][4t+u] = X[refl(8t+2u-8)], o[u] = X[refl(8t+2u-7)]
    float rb2[TI2][8];
#pragma unroll
    for (int it = 0; it < TI2; ++it) {
        int idx = tid + it * 256;
        int r = idx % NR, t = idx / NR;
        float e[12], o[12];
#pragma unroll
        for (int u = 0; u < 6; ++u) {
            float2 ve = *(const float2*)&xsE[r][4 * t + 2 * u];
            float2 vo = *(const float2*)&xsO[r][4 * t + 2 * u];
            e[2 * u] = ve.x; e[2 * u + 1] = ve.y;
            o[2 * u] = vo.x; o[2 * u + 1] = vo.y;
        }
        float lE0 = 0.f, lO0 = 0.f, hE0 = 0.f, hO0 = 0.f;
        float lE1 = 0.f, lO1 = 0.f, hE1 = 0.f, hO1 = 0.f;
#pragma unroll
        for (int k = 0; k < 10; ++k) {
            float e0 = e[k], o0 = o[k], e1 = e[k + 2], o1v = o[k + 2];
            lE0 = fmaf(e0, fb0[k], lE0);  lO0 = fmaf(o0, fa0[k], lO0);
            hE0 = fmaf(o0, fa1[k], hE0);  hO0 = fmaf(e0, fb1[k], hO0);
            lE1 = fmaf(e1, fb0[k], lE1);  lO1 = fmaf(o1v, fa0[k], lO1);
            hE1 = fmaf(o1v, fa1[k], hE1); hO1 = fmaf(e1, fb1[k], hO1);
        }
        rb2[it][0] = lE0; rb2[it][1] = lO0; rb2[it][2] = hE0; rb2[it][3] = hO0;
        rb2[it][4] = lE1; rb2[it][5] = lO1; rb2[it][6] = hE1; rb2[it][7] = hO1;
    }
    __syncthreads();

    // phase 3: write y4 over the xs region
#pragma unroll
    for (int it = 0; it < TI2; ++it) {
        int idx = tid + it * 256;
        int r = idx % NR, t = idx / NR;
        *(float4*)&y4[r][8 * t]     = make_float4(rb2[it][0], rb2[it][1], rb2[it][2], rb2[it][3]);
        *(float4*)&y4[r][8 * t + 4] = make_float4(rb2[it][4], rb2[it][5], rb2[it][6], rb2[it][7]);
    }
    __syncthreads();

    // phase 4: coldfilt + in-register q2c; thread per (ii, j) 2x2 quad
    float* llo = llout + (size_t)img * CH2 * CH2;
    float* yim = yh + (size_t)img * (6 * CQ * CQ * 2);
#pragma unroll
    for (int it = 0; it < TI4; ++it) {
        int idx = tid + it * 256;
        int ii = idx / CQ, j = idx % CQ;
        float ll00=0,ll01=0,ll10=0,ll11=0, lh00=0,lh01=0,lh10=0,lh11=0;
        float hl00=0,hl01=0,hl10=0,hl11=0, hh00=0,hh01=0,hh10=0,hh11=0;
#pragma unroll
        for (int k = 0; k < 10; ++k) {
            int ra = 4 * ii + 2 * k, rbr = ra + 1;
            float4 A = *(const float4*)&y4[ra][4 * j];    // loE,loO,hiE,hiO
            float4 B = *(const float4*)&y4[rbr][4 * j];
            float a0 = fa0[k], b0 = fb0[k], a1 = fa1[k], b1 = fb1[k];
            ll00 = fmaf(A.x, b0, ll00); ll01 = fmaf(A.y, b0, ll01);
            ll10 = fmaf(B.x, a0, ll10); ll11 = fmaf(B.y, a0, ll11);
            lh00 = fmaf(B.x, a1, lh00); lh01 = fmaf(B.y, a1, lh01);
            lh10 = fmaf(A.x, b1, lh10); lh11 = fmaf(A.y, b1, lh11);
            hl00 = fmaf(A.z, b0, hl00); hl01 = fmaf(A.w, b0, hl01);
            hl10 = fmaf(B.z, a0, hl10); hl11 = fmaf(B.w, a0, hl11);
            hh00 = fmaf(B.z, a1, hh00); hh01 = fmaf(B.w, a1, hh01);
            hh10 = fmaf(A.z, b1, hh10); hh11 = fmaf(A.w, b1, hh11);
        }
        int orow = 2 * (i0 + ii);
        if (NT_LL) {
            st_nt2(llo + (size_t)orow * CH2 + 2 * j,       make_float2(ll00, ll01));
            st_nt2(llo + (size_t)(orow + 1) * CH2 + 2 * j, make_float2(ll10, ll11));
        } else {
            *(float2*)(llo + (size_t)orow * CH2 + 2 * j)       = make_float2(ll00, ll01);
            *(float2*)(llo + (size_t)(orow + 1) * CH2 + 2 * j) = make_float2(ll10, ll11);
        }
        const int i = i0 + ii;
        const float sc = INV_SQRT2;
        float a, b, c, d;
        a = lh00 * sc; b = lh01 * sc; c = lh10 * sc; d = lh11 * sc;
        st_nt2(yim + ((size_t)(0 * CQ + i) * CQ + j) * 2, make_float2(a - d, b + c));
        st_nt2(yim + ((size_t)(5 * CQ + i) * CQ + j) * 2, make_float2(a + d, b - c));
        a = hh00 * sc; b = hh01 * sc; c = hh10 * sc; d = hh11 * sc;
        st_nt2(yim + ((size_t)(1 * CQ + i) * CQ + j) * 2, make_float2(a - d, b + c));
        st_nt2(yim + ((size_t)(4 * CQ + i) * CQ + j) * 2, make_float2(a + d, b - c));
        a = hl00 * sc; b = hl01 * sc; c = hl10 * sc; d = hl11 * sc;
        st_nt2(yim + ((size_t)(2 * CQ + i) * CQ + j) * 2, make_float2(a - d, b + c));
        st_nt2(yim + ((size_t)(3 * CQ + i) * CQ + j) * 2, make_float2(a + d, b - c));
    }
}

extern "C" void kernel_launch(void* const* d_in, const int* in_sizes, int n_in,
                              void* d_out, int out_size, void* d_ws, size_t ws_size,
                              hipStream_t stream)
{
    const float* x   = (const float*)d_in[0];
    const float* h0o = (const float*)d_in[1];
    const float* h1o = (const float*)d_in[2];
    const float* h0a = (const float*)d_in[3];
    const float* h0b = (const float*)d_in[4];
    const float* h1a = (const float*)d_in[5];
    const float* h1b = (const float*)d_in[6];
    float* out = (float*)d_out;

    float* ll1 = (float*)d_ws;            // 16,777,216 floats (64 MB)
    float* ll2 = ll1 + 16777216;          //  4,194,304 floats (16 MB)

    float* ll3 = out;                     //  1,048,576
    float* yh1 = out + 1048576;           // 50,331,648
    float* yh2 = out + 51380224;          // 12,582,912
    float* yh3 = out + 63963136;          //  3,145,728

    dtcwt_l1<<<dim3(16, 256), 256, 0, stream>>>(x, h0o, h1o, ll1, yh1);
    dtcwt_l2<256, 8, false, 2><<<dim3(8, 256), 256, 0, stream>>>(ll1, h0a, h0b, h1a, h1b, ll2, yh2);
    dtcwt_l2<128, 8, true, 4><<<dim3(4, 256), 256, 0, stream>>>(ll2, h0a, h0b, h1a, h1b, ll3, yh3);
}

// Round 10
// 107.868 us; speedup vs baseline: 1.6740x; 1.0154x over previous
//
#include <hip/hip_runtime.h>

// DTCWT forward, J=3, B=4 C=64 H=W=256, fp32.
// XLA conv = cross-correlation (no flip). Reflection: half-sample symmetric.
// Level 2+: output pair u, even col/row: sum_k In[refl(4u+2k-8)]*h0b[k] (lo)
//           odd: refl(4u+2k-7)*h0a[k]; highpass swaps phases.
// yh outputs are write-once streams -> nontemporal stores; ll1/ll2 cached
// (re-read by the next level). LDS is a union: staging dies after the
// row-filter pass (outputs buffered in regs, static indexing).
// l1: 32-row strips, 512 threads (halo 38/32 = 1.19x, 2 blocks/CU, 16 waves).

#define INV_SQRT2 0.7071067811865476f

typedef float nvec4 __attribute__((ext_vector_type(4)));
typedef float nvec2 __attribute__((ext_vector_type(2)));

__device__ __forceinline__ int refl(int i, int n) {
    return i < 0 ? (-i - 1) : (i >= n ? (2 * n - 1 - i) : i);
}
__device__ __forceinline__ void st_nt4(float* p, float4 v) {
    nvec4 w = {v.x, v.y, v.z, v.w};
    __builtin_nontemporal_store(w, (nvec4*)p);
}
__device__ __forceinline__ void st_nt2(float* p, float2 v) {
    nvec2 w = {v.x, v.y};
    __builtin_nontemporal_store(w, (nvec2*)p);
}

// ---------------- Level 1 ----------------
// phase 1/2: xs[38][264], col c at [c+4]  (10032 floats)
// phase 3/4: slo[38][260] @0, shi[38][260] @9880  (19760 floats = 77.2 KB)
__global__ __launch_bounds__(512, 4)
void dtcwt_l1(const float* __restrict__ x,
              const float* __restrict__ h0o,
              const float* __restrict__ h1o,
              float* __restrict__ ll,     // (256,256,256) ws
              float* __restrict__ yh)     // (256,6,128,128,2)
{
    __shared__ float smem[19760];
    float (*xs)[264]  = (float(*)[264])smem;
    float (*slo)[260] = (float(*)[260])smem;
    float (*shi)[260] = (float(*)[260])(smem + 9880);

    const int img = blockIdx.y;
    const int r0  = blockIdx.x * 32;
    const int tid = threadIdx.x;

    float f0[5], f1[7];
#pragma unroll
    for (int k = 0; k < 5; ++k) f0[k] = h0o[k];
#pragma unroll
    for (int k = 0; k < 7; ++k) f1[k] = h1o[k];

    const float* xim = x + (size_t)img * 65536;

    // phase 1: stage 38 rows (row-reflected), float4 main + scalar col halo
#pragma unroll
    for (int it = 0; it < 5; ++it) {
        int idx = tid + it * 512;
        if (idx < 38 * 64) {
            int lr = idx >> 6, q = idx & 63;
            int gr = refl(r0 - 3 + lr, 256);
            float4 v = *(const float4*)(xim + gr * 256 + 4 * q);
            *(float4*)&xs[lr][4 * q + 4] = v;
        }
    }
    if (tid < 228) {   // 38 rows x cols {-3,-2,-1,256,257,258}
        int lr = tid / 6, h = tid % 6;
        int gr = refl(r0 - 3 + lr, 256);
        int c = (h < 3) ? (h - 3) : (253 + h);
        xs[lr][c + 4] = xim[gr * 256 + refl(c, 256)];
    }
    __syncthreads();

    // phase 2: row filter, 4 cols/thread, into registers.
    // s[u] = xs[lr][4cp+u] = X[refl(4cp+u-4)]; col e: lo taps s[e+2+k], hi s[e+1+k]
    float rbuf[5][8];
#pragma unroll
    for (int it = 0; it < 5; ++it) {
        int idx = tid + it * 512;
        if (idx < 38 * 64) {
            int lr = idx >> 6, cp = idx & 63;
            float4 w0 = *(const float4*)&xs[lr][4 * cp];
            float4 w1 = *(const float4*)&xs[lr][4 * cp + 4];
            float4 w2 = *(const float4*)&xs[lr][4 * cp + 8];
            float s[12] = {w0.x, w0.y, w0.z, w0.w,
                           w1.x, w1.y, w1.z, w1.w,
                           w2.x, w2.y, w2.z, w2.w};
#pragma unroll
            for (int e = 0; e < 4; ++e) {
                float alo = 0.f, ahi = 0.f;
#pragma unroll
                for (int k = 0; k < 5; ++k) alo = fmaf(f0[k], s[e + 2 + k], alo);
#pragma unroll
                for (int k = 0; k < 7; ++k) ahi = fmaf(f1[k], s[e + 1 + k], ahi);
                rbuf[it][e]     = alo;
                rbuf[it][e + 4] = ahi;
            }
        }
    }
    __syncthreads();

    // phase 3: write back over xs region
#pragma unroll
    for (int it = 0; it < 5; ++it) {
        int idx = tid + it * 512;
        if (idx < 38 * 64) {
            int lr = idx >> 6, cp = idx & 63;
            *(float4*)&slo[lr][4 * cp] =
                make_float4(rbuf[it][0], rbuf[it][1], rbuf[it][2], rbuf[it][3]);
            *(float4*)&shi[lr][4 * cp] =
                make_float4(rbuf[it][4], rbuf[it][5], rbuf[it][6], rbuf[it][7]);
        }
    }
    __syncthreads();

    // phase 4: fused col filter + q2c, 2x4 output quad per thread
    float* llim = ll + (size_t)img * 65536;
    float* yim  = yh + (size_t)img * (6 * 128 * 128 * 2);
#pragma unroll
    for (int it = 0; it < 2; ++it) {
        int idx = tid + it * 512;          // < 1024 = 16 pairs x 64 quad-cols
        int ii = idx >> 6, j = idx & 63;   // out rows 2ii,2ii+1; cols 4j..4j+3
        float sL[8][4], sH[8][4];
#pragma unroll
        for (int t = 0; t < 8; ++t) {
            float4 a = *(const float4*)&slo[2 * ii + t][4 * j];
            float4 b = *(const float4*)&shi[2 * ii + t][4 * j];
            sL[t][0] = a.x; sL[t][1] = a.y; sL[t][2] = a.z; sL[t][3] = a.w;
            sH[t][0] = b.x; sH[t][1] = b.y; sH[t][2] = b.z; sH[t][3] = b.w;
        }
        float aLL[2][4] = {}, aLH[2][4] = {}, aHL[2][4] = {}, aHH[2][4] = {};
#pragma unroll
        for (int k = 0; k < 5; ++k) {
            float fk = f0[k];
#pragma unroll
            for (int e = 0; e < 4; ++e) {
                aLL[0][e] = fmaf(fk, sL[k + 1][e], aLL[0][e]);
                aLL[1][e] = fmaf(fk, sL[k + 2][e], aLL[1][e]);
                aHL[0][e] = fmaf(fk, sH[k + 1][e], aHL[0][e]);
                aHL[1][e] = fmaf(fk, sH[k + 2][e], aHL[1][e]);
            }
        }
#pragma unroll
        for (int k = 0; k < 7; ++k) {
            float fk = f1[k];
#pragma unroll
            for (int e = 0; e < 4; ++e) {
                aLH[0][e] = fmaf(fk, sL[k][e],     aLH[0][e]);
                aLH[1][e] = fmaf(fk, sL[k + 1][e], aLH[1][e]);
                aHH[0][e] = fmaf(fk, sH[k][e],     aHH[0][e]);
                aHH[1][e] = fmaf(fk, sH[k + 1][e], aHH[1][e]);
            }
        }
        int orow = r0 + 2 * ii;
        *(float4*)(llim + (size_t)orow * 256 + 4 * j) =
            make_float4(aLL[0][0], aLL[0][1], aLL[0][2], aLL[0][3]);
        *(float4*)(llim + (size_t)(orow + 1) * 256 + 4 * j) =
            make_float4(aLL[1][0], aLL[1][1], aLL[1][2], aLL[1][3]);
        const int i = (r0 >> 1) + ii;
        const float sc = INV_SQRT2;
        // band -> (plane1, plane2): LH->(0,5), HH->(1,4), HL->(2,3)
#pragma unroll
        for (int band = 0; band < 3; ++band) {
            const float (*S)[4] = (band == 0) ? aLH : (band == 1) ? aHH : aHL;
            int o1 = (band == 0) ? 0 : (band == 1) ? 1 : 2;
            int o2 = (band == 0) ? 5 : (band == 1) ? 4 : 3;
            float r1[4], r2[4];
#pragma unroll
            for (int jj = 0; jj < 2; ++jj) {
                float a = S[0][2 * jj] * sc, b = S[0][2 * jj + 1] * sc;
                float c = S[1][2 * jj] * sc, d = S[1][2 * jj + 1] * sc;
                r1[2 * jj] = a - d; r1[2 * jj + 1] = b + c;
                r2[2 * jj] = a + d; r2[2 * jj + 1] = b - c;
            }
            st_nt4(yim + (size_t)(o1 * 128 + i) * 256 + 4 * j,
                   make_float4(r1[0], r1[1], r1[2], r1[3]));
            st_nt4(yim + (size_t)(o2 * 128 + i) * 256 + 4 * j,
                   make_float4(r2[0], r2[1], r2[2], r2[3]));
        }
    }
}

// ---------------- Levels 2+ ----------------
template <int CI, int NI, bool NT_LL, int MW>
__global__ __launch_bounds__(256, MW)
void dtcwt_l2(const float* __restrict__ llin,
              const float* __restrict__ h0a, const float* __restrict__ h0b,
              const float* __restrict__ h1a, const float* __restrict__ h1b,
              float* __restrict__ llout,   // (256, CI/2, CI/2)
              float* __restrict__ yh)      // (256, 6, CI/4, CI/4, 2)
{
    constexpr int CH2  = CI / 2;
    constexpr int CQ   = CI / 4;
    constexpr int Nj   = CI / 4;
    constexpr int NR   = 4 * NI + 16;
    constexpr int LDE  = CI / 2 + 14;         // %32 == 14 -> 2-way (free)
    constexpr int LDY4 = 4 * Nj + 4;
    constexpr int XSZ  = NR * LDE;
    constexpr int SM   = (2 * XSZ > NR * LDY4) ? 2 * XSZ : NR * LDY4;
    constexpr int TIS  = NR * (CI / 4) / 256; // stage iters (exact)
    constexpr int TI2  = NR * (Nj / 2) / 256; // rowdfilt iters (exact)
    constexpr int TI4  = NI * CQ / 256;       // coldfilt iters (exact)

    __shared__ float smem[SM];
    float (*xsE)[LDE] = (float(*)[LDE])smem;
    float (*xsO)[LDE] = (float(*)[LDE])(smem + XSZ);
    float (*y4)[LDY4] = (float(*)[LDY4])smem;   // [r][4j+{loE,loO,hiE,hiO}]

    const int img = blockIdx.y;
    const int i0  = blockIdx.x * NI;
    const int tid = threadIdx.x;

    float fa0[10], fb0[10], fa1[10], fb1[10];
#pragma unroll
    for (int k = 0; k < 10; ++k) {
        fa0[k] = h0a[k]; fb0[k] = h0b[k];
        fa1[k] = h1a[k]; fb1[k] = h1b[k];
    }

    const float* xim = llin + (size_t)img * CI * CI;

    // phase 1: stage de-interleaved even/odd cols; xsE[r][m+4]=X[refl(2m)]
#pragma unroll
    for (int it = 0; it < TIS; ++it) {
        int idx = tid + it * 256;
        int lr = idx / (CI / 4), q = idx % (CI / 4);
        int gr = refl(4 * i0 - 8 + lr, CI);
        float4 v = *(const float4*)(xim + (size_t)gr * CI + 4 * q);
        *(float2*)&xsE[lr][2 * q + 4] = make_float2(v.x, v.z);
        *(float2*)&xsO[lr][2 * q + 4] = make_float2(v.y, v.w);
    }
    for (int idx = tid; idx < NR * 8; idx += 256) {  // m in {-4..-1, CI/2..CI/2+3}
        int lr = idx >> 3, h = idx & 7;
        int gr = refl(4 * i0 - 8 + lr, CI);
        int m = (h < 4) ? (h - 4) : (CI / 2 + h - 4);
        xsE[lr][m + 4] = xim[(size_t)gr * CI + refl(2 * m, CI)];
        xsO[lr][m + 4] = xim[(size_t)gr * CI + refl(2 * m + 1, CI)];
    }
    __syncthreads();

    // phase 2: rowdfilt into registers, 2 column-pairs (j0=2t, j0+1) per item.
    // e[u] = xsE[r][4t+u] = X[refl(8t+2u-8)], o[u] = X[refl(8t+2u-7)]
    float rb2[TI2][8];
#pragma unroll
    for (int it = 0; it < TI2; ++it) {
        int idx = tid + it * 256;
        int r = idx % NR, t = idx / NR;
        float e[12], o[12];
#pragma unroll
        for (int u = 0; u < 6; ++u) {
            float2 ve = *(const float2*)&xsE[r][4 * t + 2 * u];
            float2 vo = *(const float2*)&xsO[r][4 * t + 2 * u];
            e[2 * u] = ve.x; e[2 * u + 1] = ve.y;
            o[2 * u] = vo.x; o[2 * u + 1] = vo.y;
        }
        float lE0 = 0.f, lO0 = 0.f, hE0 = 0.f, hO0 = 0.f;
        float lE1 = 0.f, lO1 = 0.f, hE1 = 0.f, hO1 = 0.f;
#pragma unroll
        for (int k = 0; k < 10; ++k) {
            float e0 = e[k], o0 = o[k], e1 = e[k + 2], o1v = o[k + 2];
            lE0 = fmaf(e0, fb0[k], lE0);  lO0 = fmaf(o0, fa0[k], lO0);
            hE0 = fmaf(o0, fa1[k], hE0);  hO0 = fmaf(e0, fb1[k], hO0);
            lE1 = fmaf(e1, fb0[k], lE1);  lO1 = fmaf(o1v, fa0[k], lO1);
            hE1 = fmaf(o1v, fa1[k], hE1); hO1 = fmaf(e1, fb1[k], hO1);
        }
        rb2[it][0] = lE0; rb2[it][1] = lO0; rb2[it][2] = hE0; rb2[it][3] = hO0;
        rb2[it][4] = lE1; rb2[it][5] = lO1; rb2[it][6] = hE1; rb2[it][7] = hO1;
    }
    __syncthreads();

    // phase 3: write y4 over the xs region
#pragma unroll
    for (int it = 0; it < TI2; ++it) {
        int idx = tid + it * 256;
        int r = idx % NR, t = idx / NR;
        *(float4*)&y4[r][8 * t]     = make_float4(rb2[it][0], rb2[it][1], rb2[it][2], rb2[it][3]);
        *(float4*)&y4[r][8 * t + 4] = make_float4(rb2[it][4], rb2[it][5], rb2[it][6], rb2[it][7]);
    }
    __syncthreads();

    // phase 4: coldfilt + in-register q2c; thread per (ii, j) 2x2 quad
    float* llo = llout + (size_t)img * CH2 * CH2;
    float* yim = yh + (size_t)img * (6 * CQ * CQ * 2);
#pragma unroll
    for (int it = 0; it < TI4; ++it) {
        int idx = tid + it * 256;
        int ii = idx / CQ, j = idx % CQ;
        float ll00=0,ll01=0,ll10=0,ll11=0, lh00=0,lh01=0,lh10=0,lh11=0;
        float hl00=0,hl01=0,hl10=0,hl11=0, hh00=0,hh01=0,hh10=0,hh11=0;
#pragma unroll
        for (int k = 0; k < 10; ++k) {
            int ra = 4 * ii + 2 * k, rbr = ra + 1;
            float4 A = *(const float4*)&y4[ra][4 * j];    // loE,loO,hiE,hiO
            float4 B = *(const float4*)&y4[rbr][4 * j];
            float a0 = fa0[k], b0 = fb0[k], a1 = fa1[k], b1 = fb1[k];
            ll00 = fmaf(A.x, b0, ll00); ll01 = fmaf(A.y, b0, ll01);
            ll10 = fmaf(B.x, a0, ll10); ll11 = fmaf(B.y, a0, ll11);
            lh00 = fmaf(B.x, a1, lh00); lh01 = fmaf(B.y, a1, lh01);
            lh10 = fmaf(A.x, b1, lh10); lh11 = fmaf(A.y, b1, lh11);
            hl00 = fmaf(A.z, b0, hl00); hl01 = fmaf(A.w, b0, hl01);
            hl10 = fmaf(B.z, a0, hl10); hl11 = fmaf(B.w, a0, hl11);
            hh00 = fmaf(B.z, a1, hh00); hh01 = fmaf(B.w, a1, hh01);
            hh10 = fmaf(A.z, b1, hh10); hh11 = fmaf(A.w, b1, hh11);
        }
        int orow = 2 * (i0 + ii);
        if (NT_LL) {
            st_nt2(llo + (size_t)orow * CH2 + 2 * j,       make_float2(ll00, ll01));
            st_nt2(llo + (size_t)(orow + 1) * CH2 + 2 * j, make_float2(ll10, ll11));
        } else {
            *(float2*)(llo + (size_t)orow * CH2 + 2 * j)       = make_float2(ll00, ll01);
            *(float2*)(llo + (size_t)(orow + 1) * CH2 + 2 * j) = make_float2(ll10, ll11);
        }
        const int i = i0 + ii;
        const float sc = INV_SQRT2;
        float a, b, c, d;
        a = lh00 * sc; b = lh01 * sc; c = lh10 * sc; d = lh11 * sc;
        st_nt2(yim + ((size_t)(0 * CQ + i) * CQ + j) * 2, make_float2(a - d, b + c));
        st_nt2(yim + ((size_t)(5 * CQ + i) * CQ + j) * 2, make_float2(a + d, b - c));
        a = hh00 * sc; b = hh01 * sc; c = hh10 * sc; d = hh11 * sc;
        st_nt2(yim + ((size_t)(1 * CQ + i) * CQ + j) * 2, make_float2(a - d, b + c));
        st_nt2(yim + ((size_t)(4 * CQ + i) * CQ + j) * 2, make_float2(a + d, b - c));
        a = hl00 * sc; b = hl01 * sc; c = hl10 * sc; d = hl11 * sc;
        st_nt2(yim + ((size_t)(2 * CQ + i) * CQ + j) * 2, make_float2(a - d, b + c));
        st_nt2(yim + ((size_t)(3 * CQ + i) * CQ + j) * 2, make_float2(a + d, b - c));
    }
}

extern "C" void kernel_launch(void* const* d_in, const int* in_sizes, int n_in,
                              void* d_out, int out_size, void* d_ws, size_t ws_size,
                              hipStream_t stream)
{
    const float* x   = (const float*)d_in[0];
    const float* h0o = (const float*)d_in[1];
    const float* h1o = (const float*)d_in[2];
    const float* h0a = (const float*)d_in[3];
    const float* h0b = (const float*)d_in[4];
    const float* h1a = (const float*)d_in[5];
    const float* h1b = (const float*)d_in[6];
    float* out = (float*)d_out;

    float* ll1 = (float*)d_ws;            // 16,777,216 floats (64 MB)
    float* ll2 = ll1 + 16777216;          //  4,194,304 floats (16 MB)

    float* ll3 = out;                     //  1,048,576
    float* yh1 = out + 1048576;           // 50,331,648
    float* yh2 = out + 51380224;          // 12,582,912
    float* yh3 = out + 63963136;          //  3,145,728

    dtcwt_l1<<<dim3(8, 256), 512, 0, stream>>>(x, h0o, h1o, ll1, yh1);
    dtcwt_l2<256, 8, false, 2><<<dim3(8, 256), 256, 0, stream>>>(ll1, h0a, h0b, h1a, h1b, ll2, yh2);
    dtcwt_l2<128, 8, true, 4><<<dim3(4, 256), 256, 0, stream>>>(ll2, h0a, h0b, h1a, h1b, ll3, yh3);
}